// Round 2
// baseline (4178.199 us; speedup 1.0000x reference)
//
#include <hip/hip_runtime.h>
#include <math.h>

#define B_ 512
#define C_ 200
#define D_ 512
#define E_ 256
#define V_ 8192
#define G_ 2048
#define L_ 16

__device__ __forceinline__ float sigm(float x) { return 1.0f / (1.0f + expf(-x)); }

// ---------------------------------------------------------------------------
// init: h0 = c0 = mean over valid context rows; tok0 = 1
// ---------------------------------------------------------------------------
__global__ __launch_bounds__(256) void k_init(const float* __restrict__ ctx,
                                              const int* __restrict__ counts,
                                              float* __restrict__ h,
                                              float* __restrict__ c,
                                              int* __restrict__ tok) {
    int b = blockIdx.x;
    int t = threadIdx.x;
    int cnt = counts[b];
    const float* base = ctx + (size_t)b * C_ * D_;
    float s0 = 0.f, s1 = 0.f;
    for (int cc = 0; cc < cnt; ++cc) {
        s0 += base[(size_t)cc * D_ + t];
        s1 += base[(size_t)cc * D_ + t + 256];
    }
    float inv = 1.0f / (float)cnt;
    float v0 = s0 * inv, v1 = s1 * inv;
    h[b * D_ + t] = v0;        h[b * D_ + t + 256] = v1;
    c[b * D_ + t] = v0;        c[b * D_ + t + 256] = v1;
    if (t == 0) tok[b] = 1;
}

// ---------------------------------------------------------------------------
// logits = h @ W_proj^T + b_proj  (M=512, N=8192, K=512)
// 128x128 tile, BK=16, 8x8 per thread. Fragment map: 2-way/broadcast LDS reads.
// ---------------------------------------------------------------------------
__global__ __launch_bounds__(256, 2) void k_logits(const float* __restrict__ A,
                                                   const float* __restrict__ Bw,
                                                   const float* __restrict__ bias,
                                                   float* __restrict__ Co) {
    __shared__ float As[16][128 + 4];
    __shared__ float Bs[16][128 + 4];
    int t = threadIdx.x;
    int m0 = blockIdx.y * 128;
    int n0 = blockIdx.x * 128;
    int m1 = (t & 15) * 4;
    int n1 = (t >> 4) * 4;
    int srow = t >> 2;          // 0..63
    int skc = (t & 3) * 4;      // 0,4,8,12
    float acc[8][8] = {};
    for (int kt = 0; kt < D_; kt += 16) {
        float4 a0 = *(const float4*)&A[(size_t)(m0 + srow) * D_ + kt + skc];
        float4 a1 = *(const float4*)&A[(size_t)(m0 + srow + 64) * D_ + kt + skc];
        float4 b0 = *(const float4*)&Bw[(size_t)(n0 + srow) * D_ + kt + skc];
        float4 b1 = *(const float4*)&Bw[(size_t)(n0 + srow + 64) * D_ + kt + skc];
        __syncthreads();
        As[skc + 0][srow] = a0.x; As[skc + 1][srow] = a0.y;
        As[skc + 2][srow] = a0.z; As[skc + 3][srow] = a0.w;
        As[skc + 0][srow + 64] = a1.x; As[skc + 1][srow + 64] = a1.y;
        As[skc + 2][srow + 64] = a1.z; As[skc + 3][srow + 64] = a1.w;
        Bs[skc + 0][srow] = b0.x; Bs[skc + 1][srow] = b0.y;
        Bs[skc + 2][srow] = b0.z; Bs[skc + 3][srow] = b0.w;
        Bs[skc + 0][srow + 64] = b1.x; Bs[skc + 1][srow + 64] = b1.y;
        Bs[skc + 2][srow + 64] = b1.z; Bs[skc + 3][srow + 64] = b1.w;
        __syncthreads();
#pragma unroll
        for (int k = 0; k < 16; ++k) {
            float4 af0 = *(const float4*)&As[k][m1];
            float4 af1 = *(const float4*)&As[k][m1 + 64];
            float4 bf0 = *(const float4*)&Bs[k][n1];
            float4 bf1 = *(const float4*)&Bs[k][n1 + 64];
            float a[8] = {af0.x, af0.y, af0.z, af0.w, af1.x, af1.y, af1.z, af1.w};
            float b[8] = {bf0.x, bf0.y, bf0.z, bf0.w, bf1.x, bf1.y, bf1.z, bf1.w};
#pragma unroll
            for (int i = 0; i < 8; ++i)
#pragma unroll
                for (int j = 0; j < 8; ++j) acc[i][j] += a[i] * b[j];
        }
    }
    float4 bias0 = *(const float4*)&bias[n0 + n1];
    float4 bias1 = *(const float4*)&bias[n0 + n1 + 64];
    float bj[8] = {bias0.x, bias0.y, bias0.z, bias0.w, bias1.x, bias1.y, bias1.z, bias1.w};
#pragma unroll
    for (int i = 0; i < 8; ++i) {
        int m = m0 + ((i < 4) ? (m1 + i) : (m1 + 64 + i - 4));
        float4 v0 = make_float4(acc[i][0] + bj[0], acc[i][1] + bj[1],
                                acc[i][2] + bj[2], acc[i][3] + bj[3]);
        float4 v1 = make_float4(acc[i][4] + bj[4], acc[i][5] + bj[5],
                                acc[i][6] + bj[6], acc[i][7] + bj[7]);
        *(float4*)&Co[(size_t)m * V_ + n0 + n1] = v0;
        *(float4*)&Co[(size_t)m * V_ + n0 + n1 + 64] = v1;
    }
}

// ---------------------------------------------------------------------------
// q = h @ W_attn^T   (M=512, N=512, K=512); 64x64 tile, BK=16, 4x4/thread
// ---------------------------------------------------------------------------
__global__ __launch_bounds__(256, 4) void k_qproj(const float* __restrict__ A,
                                                  const float* __restrict__ Bw,
                                                  float* __restrict__ Cq) {
    __shared__ float As[16][64 + 4];
    __shared__ float Bs[16][64 + 4];
    int t = threadIdx.x;
    int m0 = blockIdx.y * 64;
    int n0 = blockIdx.x * 64;
    int m1 = (t & 15) * 4;
    int n1 = (t >> 4) * 4;
    int srow = t >> 2;
    int skc = (t & 3) * 4;
    float acc[4][4] = {};
    for (int kt = 0; kt < D_; kt += 16) {
        float4 a0 = *(const float4*)&A[(size_t)(m0 + srow) * D_ + kt + skc];
        float4 b0 = *(const float4*)&Bw[(size_t)(n0 + srow) * D_ + kt + skc];
        __syncthreads();
        As[skc + 0][srow] = a0.x; As[skc + 1][srow] = a0.y;
        As[skc + 2][srow] = a0.z; As[skc + 3][srow] = a0.w;
        Bs[skc + 0][srow] = b0.x; Bs[skc + 1][srow] = b0.y;
        Bs[skc + 2][srow] = b0.z; Bs[skc + 3][srow] = b0.w;
        __syncthreads();
#pragma unroll
        for (int k = 0; k < 16; ++k) {
            float4 af = *(const float4*)&As[k][m1];
            float4 bf = *(const float4*)&Bs[k][n1];
            float a[4] = {af.x, af.y, af.z, af.w};
            float b[4] = {bf.x, bf.y, bf.z, bf.w};
#pragma unroll
            for (int i = 0; i < 4; ++i)
#pragma unroll
                for (int j = 0; j < 4; ++j) acc[i][j] += a[i] * b[j];
        }
    }
#pragma unroll
    for (int i = 0; i < 4; ++i) {
        float4 v = make_float4(acc[i][0], acc[i][1], acc[i][2], acc[i][3]);
        *(float4*)&Cq[(size_t)(m0 + m1 + i) * D_ + n0 + n1] = v;
    }
}

// ---------------------------------------------------------------------------
// attention: one block per batch row. scores -> softmax -> weighted sum
// ---------------------------------------------------------------------------
__global__ __launch_bounds__(256) void k_attn(const float* __restrict__ ctx,
                                              const int* __restrict__ counts,
                                              const float* __restrict__ q,
                                              float* __restrict__ ctxv) {
    __shared__ float w_lds[C_];
    __shared__ float redm[4];
    __shared__ float reds[4];
    int b = blockIdx.x;
    int t = threadIdx.x;
    int lane = t & 63;
    int wv = t >> 6;
    int cnt = counts[b];
    const float* cb = ctx + (size_t)b * C_ * D_;

    float4 q0 = *(const float4*)&q[(size_t)b * D_ + lane * 4];
    float4 q1 = *(const float4*)&q[(size_t)b * D_ + lane * 4 + 256];

    for (int cc = wv; cc < cnt; cc += 4) {
        const float* row = cb + (size_t)cc * D_;
        float4 x0 = *(const float4*)&row[lane * 4];
        float4 x1 = *(const float4*)&row[lane * 4 + 256];
        float s = x0.x * q0.x + x0.y * q0.y + x0.z * q0.z + x0.w * q0.w +
                  x1.x * q1.x + x1.y * q1.y + x1.z * q1.z + x1.w * q1.w;
#pragma unroll
        for (int off = 32; off; off >>= 1) s += __shfl_down(s, off);
        if (lane == 0) w_lds[cc] = s;
    }
    __syncthreads();

    float sv = (t < cnt) ? w_lds[t] : -INFINITY;
    float m = sv;
#pragma unroll
    for (int off = 32; off; off >>= 1) m = fmaxf(m, __shfl_xor(m, off));
    if (lane == 0) redm[wv] = m;
    __syncthreads();
    m = fmaxf(fmaxf(redm[0], redm[1]), fmaxf(redm[2], redm[3]));
    float e = (t < cnt) ? expf(sv - m) : 0.0f;
    float ps = e;
#pragma unroll
    for (int off = 32; off; off >>= 1) ps += __shfl_xor(ps, off);
    if (lane == 0) reds[wv] = ps;
    if (t < cnt) w_lds[t] = e;
    __syncthreads();
    float inv = 1.0f / (reds[0] + reds[1] + reds[2] + reds[3]);

    float a0 = 0.f, a1 = 0.f;
    for (int cc = 0; cc < cnt; ++cc) {
        float wc = w_lds[cc];
        a0 += wc * cb[(size_t)cc * D_ + t];
        a1 += wc * cb[(size_t)cc * D_ + t + 256];
    }
    ctxv[(size_t)b * D_ + t] = a0 * inv;
    ctxv[(size_t)b * D_ + t + 256] = a1 * inv;
}

// ---------------------------------------------------------------------------
// gates GEMM + fused LSTM cell. 64x64 tile, BK=16, 4x4/thread.
// A[b,k]: k<256 -> emb[tok[b]][k]; k<768 -> ctxv[b,k-256]; else h_in[b,k-768]
// B rows reordered: tile col r -> orig gate row go = (r&3)*512 + (r>>2)
// ---------------------------------------------------------------------------
__global__ __launch_bounds__(256, 4) void k_gates(const int* __restrict__ tok,
                                                  const float* __restrict__ emb,
                                                  const float* __restrict__ ctxv,
                                                  const float* __restrict__ h_in,
                                                  const float* __restrict__ W_ih,
                                                  const float* __restrict__ b_ih,
                                                  const float* __restrict__ W_hh,
                                                  const float* __restrict__ b_hh,
                                                  float* __restrict__ cbuf,
                                                  float* __restrict__ h_out) {
    __shared__ float As[16][64 + 4];
    __shared__ float Bs[16][64 + 4];
    int t = threadIdx.x;
    int m0 = blockIdx.y * 64;
    int n0 = blockIdx.x * 64;
    int m1 = (t & 15) * 4;
    int n1 = (t >> 4) * 4;
    int srow = t >> 2;
    int skc = (t & 3) * 4;
    int arow = m0 + srow;
    int atok = tok[arow];
    int r = n0 + srow;
    int go = ((r & 3) << 9) + (r >> 2);
    float acc[4][4] = {};
    for (int kt = 0; kt < 1280; kt += 16) {
        int kk = kt + skc;
        float4 a0;
        if (kk < 256) {
            a0 = *(const float4*)&emb[(size_t)atok * E_ + kk];
        } else if (kk < 768) {
            a0 = *(const float4*)&ctxv[(size_t)arow * D_ + kk - 256];
        } else {
            a0 = *(const float4*)&h_in[(size_t)arow * D_ + kk - 768];
        }
        float4 b0;
        if (kk < 768) {
            b0 = *(const float4*)&W_ih[(size_t)go * 768 + kk];
        } else {
            b0 = *(const float4*)&W_hh[(size_t)go * D_ + kk - 768];
        }
        __syncthreads();
        As[skc + 0][srow] = a0.x; As[skc + 1][srow] = a0.y;
        As[skc + 2][srow] = a0.z; As[skc + 3][srow] = a0.w;
        Bs[skc + 0][srow] = b0.x; Bs[skc + 1][srow] = b0.y;
        Bs[skc + 2][srow] = b0.z; Bs[skc + 3][srow] = b0.w;
        __syncthreads();
#pragma unroll
        for (int k = 0; k < 16; ++k) {
            float4 af = *(const float4*)&As[k][m1];
            float4 bf = *(const float4*)&Bs[k][n1];
            float a[4] = {af.x, af.y, af.z, af.w};
            float b[4] = {bf.x, bf.y, bf.z, bf.w};
#pragma unroll
            for (int i = 0; i < 4; ++i)
#pragma unroll
                for (int j = 0; j < 4; ++j) acc[i][j] += a[i] * b[j];
        }
    }
    int d = (n0 + n1) >> 2;
    float bi = b_ih[d] + b_hh[d];
    float bf_ = b_ih[512 + d] + b_hh[512 + d];
    float bg = b_ih[1024 + d] + b_hh[1024 + d];
    float bo = b_ih[1536 + d] + b_hh[1536 + d];
#pragma unroll
    for (int i = 0; i < 4; ++i) {
        int b = m0 + m1 + i;
        float ig = sigm(acc[i][0] + bi);
        float fg = sigm(acc[i][1] + bf_);
        float gg = tanhf(acc[i][2] + bg);
        float og = sigm(acc[i][3] + bo);
        float cn = fg * cbuf[(size_t)b * D_ + d] + ig * gg;
        cbuf[(size_t)b * D_ + d] = cn;
        h_out[(size_t)b * D_ + d] = og * tanhf(cn);
    }
}

// ---------------------------------------------------------------------------
// argmax over V per batch row; first-index tie-break (matches jnp.argmax)
// ---------------------------------------------------------------------------
__global__ __launch_bounds__(256) void k_argmax(const float* __restrict__ logits,
                                                int* __restrict__ tok) {
    __shared__ float rv[4];
    __shared__ int ri[4];
    int b = blockIdx.x;
    int t = threadIdx.x;
    int lane = t & 63;
    int wv = t >> 6;
    const float* p = logits + (size_t)b * V_;
    float best = -INFINITY;
    int bi = 0x7fffffff;
    for (int v = t; v < V_; v += 256) {
        float x = p[v];
        if (x > best) { best = x; bi = v; }
    }
#pragma unroll
    for (int off = 32; off; off >>= 1) {
        float ov = __shfl_down(best, off);
        int oi = __shfl_down(bi, off);
        if (ov > best || (ov == best && oi < bi)) { best = ov; bi = oi; }
    }
    if (lane == 0) { rv[wv] = best; ri[wv] = bi; }
    __syncthreads();
    if (t == 0) {
        for (int w = 1; w < 4; ++w) {
            if (rv[w] > best || (rv[w] == best && ri[w] < bi)) { best = rv[w]; bi = ri[w]; }
        }
        tok[b] = bi;
    }
}

// ---------------------------------------------------------------------------
extern "C" void kernel_launch(void* const* d_in, const int* in_sizes, int n_in,
                              void* d_out, int out_size, void* d_ws, size_t ws_size,
                              hipStream_t stream) {
    const float* ctx    = (const float*)d_in[0];
    const int*   counts = (const int*)d_in[1];
    const float* emb    = (const float*)d_in[3];
    const float* W_attn = (const float*)d_in[4];
    const float* W_ih   = (const float*)d_in[5];
    const float* b_ih   = (const float*)d_in[6];
    const float* W_hh   = (const float*)d_in[7];
    const float* b_hh   = (const float*)d_in[8];
    const float* W_proj = (const float*)d_in[9];
    const float* b_proj = (const float*)d_in[10];
    float* out = (float*)d_out;

    float* hA   = (float*)d_ws;            // [B,D]
    float* hB   = hA + B_ * D_;            // [B,D]
    float* cbuf = hB + B_ * D_;            // [B,D]
    float* qbuf = cbuf + B_ * D_;          // [B,D]
    float* ctxv = qbuf + B_ * D_;          // [B,D]
    int*   tok  = (int*)(ctxv + B_ * D_);  // [B]

    hipMemsetAsync(out, 0, (size_t)B_ * V_ * sizeof(float), stream);

    k_init<<<B_, 256, 0, stream>>>(ctx, counts, hA, cbuf, tok);

    float* hin = hA;
    float* hout = hB;
    for (int t = 1; t < L_; ++t) {
        k_qproj<<<dim3(D_ / 64, B_ / 64), 256, 0, stream>>>(hin, W_attn, qbuf);
        k_attn<<<B_, 256, 0, stream>>>(ctx, counts, qbuf, ctxv);
        k_gates<<<dim3(G_ / 64, B_ / 64), 256, 0, stream>>>(tok, emb, ctxv, hin,
                                                            W_ih, b_ih, W_hh, b_hh,
                                                            cbuf, hout);
        float* slab = out + (size_t)t * B_ * V_;
        k_logits<<<dim3(V_ / 128, B_ / 128), 256, 0, stream>>>(hout, W_proj, b_proj, slab);
        if (t < L_ - 1) k_argmax<<<B_, 256, 0, stream>>>(slab, tok);
        float* tmp = hin; hin = hout; hout = tmp;
    }
}

// Round 3
// 3565.765 us; speedup vs baseline: 1.1718x; 1.1718x over previous
//
#include <hip/hip_runtime.h>
#include <math.h>

#define B_ 512
#define C_ 200
#define D_ 512
#define E_ 256
#define V_ 8192
#define G_ 2048
#define L_ 16

__device__ __forceinline__ float sigm(float x) { return 1.0f / (1.0f + expf(-x)); }

// ---------------------------------------------------------------------------
// init: h0 = c0 = mean over valid context rows; tok0 = 1
// ---------------------------------------------------------------------------
__global__ __launch_bounds__(256) void k_init(const float* __restrict__ ctx,
                                              const int* __restrict__ counts,
                                              float* __restrict__ h,
                                              float* __restrict__ c,
                                              int* __restrict__ tok) {
    int b = blockIdx.x;
    int t = threadIdx.x;
    int cnt = counts[b];
    const float* base = ctx + (size_t)b * C_ * D_;
    float s0 = 0.f, s1 = 0.f;
    for (int cc = 0; cc < cnt; ++cc) {
        s0 += base[(size_t)cc * D_ + t];
        s1 += base[(size_t)cc * D_ + t + 256];
    }
    float inv = 1.0f / (float)cnt;
    float v0 = s0 * inv, v1 = s1 * inv;
    h[b * D_ + t] = v0;        h[b * D_ + t + 256] = v1;
    c[b * D_ + t] = v0;        c[b * D_ + t + 256] = v1;
    if (t == 0) tok[b] = 1;
}

// ---------------------------------------------------------------------------
// logits = h @ W_proj^T + b_proj  (M=512, N=8192, K=512)
// 64M x 128N tile, BK=32, 256 threads, 4x8/thread. Reg-staged pipeline.
// grid = (8192/128, 512/64) = (64, 8) = 512 blocks -> 2/CU.
// ---------------------------------------------------------------------------
__global__ __launch_bounds__(256, 2) void k_logits(const float* __restrict__ A,
                                                   const float* __restrict__ Bw,
                                                   const float* __restrict__ bias,
                                                   float* __restrict__ Co) {
    __shared__ float As[32][64];
    __shared__ float Bs[32][128];
    int t = threadIdx.x;
    int m0 = blockIdx.y * 64;
    int n0 = blockIdx.x * 128;
    int m1 = (t & 15) * 4;
    int n1 = (t >> 4) * 8;
    int asrow = t & 63, askc = (t >> 6) * 8;          // 2 float4 along k
    int bsrow = t & 127, bskc = (t >> 7) * 16;        // 4 float4 along k
    const float* Ap = A + (size_t)(m0 + asrow) * D_ + askc;
    const float* Bp = Bw + (size_t)(n0 + bsrow) * D_ + bskc;

    float4 ra0 = *(const float4*)(Ap);
    float4 ra1 = *(const float4*)(Ap + 4);
    float4 rb0 = *(const float4*)(Bp);
    float4 rb1 = *(const float4*)(Bp + 4);
    float4 rb2 = *(const float4*)(Bp + 8);
    float4 rb3 = *(const float4*)(Bp + 12);

    float acc[4][8] = {};
    for (int kt = 0; kt < D_; kt += 32) {
        __syncthreads();
        As[askc + 0][asrow] = ra0.x; As[askc + 1][asrow] = ra0.y;
        As[askc + 2][asrow] = ra0.z; As[askc + 3][asrow] = ra0.w;
        As[askc + 4][asrow] = ra1.x; As[askc + 5][asrow] = ra1.y;
        As[askc + 6][asrow] = ra1.z; As[askc + 7][asrow] = ra1.w;
        Bs[bskc + 0][bsrow] = rb0.x;  Bs[bskc + 1][bsrow] = rb0.y;
        Bs[bskc + 2][bsrow] = rb0.z;  Bs[bskc + 3][bsrow] = rb0.w;
        Bs[bskc + 4][bsrow] = rb1.x;  Bs[bskc + 5][bsrow] = rb1.y;
        Bs[bskc + 6][bsrow] = rb1.z;  Bs[bskc + 7][bsrow] = rb1.w;
        Bs[bskc + 8][bsrow] = rb2.x;  Bs[bskc + 9][bsrow] = rb2.y;
        Bs[bskc + 10][bsrow] = rb2.z; Bs[bskc + 11][bsrow] = rb2.w;
        Bs[bskc + 12][bsrow] = rb3.x; Bs[bskc + 13][bsrow] = rb3.y;
        Bs[bskc + 14][bsrow] = rb3.z; Bs[bskc + 15][bsrow] = rb3.w;
        __syncthreads();
        if (kt + 32 < D_) {
            ra0 = *(const float4*)(Ap + kt + 32);
            ra1 = *(const float4*)(Ap + kt + 36);
            rb0 = *(const float4*)(Bp + kt + 32);
            rb1 = *(const float4*)(Bp + kt + 36);
            rb2 = *(const float4*)(Bp + kt + 40);
            rb3 = *(const float4*)(Bp + kt + 44);
        }
#pragma unroll
        for (int k = 0; k < 32; ++k) {
            float4 af = *(const float4*)&As[k][m1];
            float4 bf0 = *(const float4*)&Bs[k][n1];
            float4 bf1 = *(const float4*)&Bs[k][n1 + 4];
            float a[4] = {af.x, af.y, af.z, af.w};
            float b[8] = {bf0.x, bf0.y, bf0.z, bf0.w, bf1.x, bf1.y, bf1.z, bf1.w};
#pragma unroll
            for (int i = 0; i < 4; ++i)
#pragma unroll
                for (int j = 0; j < 8; ++j) acc[i][j] += a[i] * b[j];
        }
    }
    float4 bias0 = *(const float4*)&bias[n0 + n1];
    float4 bias1 = *(const float4*)&bias[n0 + n1 + 4];
    float bj[8] = {bias0.x, bias0.y, bias0.z, bias0.w, bias1.x, bias1.y, bias1.z, bias1.w};
#pragma unroll
    for (int i = 0; i < 4; ++i) {
        int m = m0 + m1 + i;
        float4 v0 = make_float4(acc[i][0] + bj[0], acc[i][1] + bj[1],
                                acc[i][2] + bj[2], acc[i][3] + bj[3]);
        float4 v1 = make_float4(acc[i][4] + bj[4], acc[i][5] + bj[5],
                                acc[i][6] + bj[6], acc[i][7] + bj[7]);
        *(float4*)&Co[(size_t)m * V_ + n0 + n1] = v0;
        *(float4*)&Co[(size_t)m * V_ + n0 + n1 + 4] = v1;
    }
}

// ---------------------------------------------------------------------------
// q = h @ W_attn^T  (512x512x512). 64x64 tile, BK=32, 4x4/thread, pipelined.
// ---------------------------------------------------------------------------
__global__ __launch_bounds__(256, 2) void k_qproj(const float* __restrict__ A,
                                                  const float* __restrict__ Bw,
                                                  float* __restrict__ Cq) {
    __shared__ float As[32][64];
    __shared__ float Bs[32][64];
    int t = threadIdx.x;
    int m0 = blockIdx.y * 64;
    int n0 = blockIdx.x * 64;
    int m1 = (t & 15) * 4;
    int n1 = (t >> 4) * 4;
    int srow = t & 63, skc = (t >> 6) * 8;
    const float* Ap = A + (size_t)(m0 + srow) * D_ + skc;
    const float* Bp = Bw + (size_t)(n0 + srow) * D_ + skc;

    float4 ra0 = *(const float4*)(Ap);
    float4 ra1 = *(const float4*)(Ap + 4);
    float4 rb0 = *(const float4*)(Bp);
    float4 rb1 = *(const float4*)(Bp + 4);

    float acc[4][4] = {};
    for (int kt = 0; kt < D_; kt += 32) {
        __syncthreads();
        As[skc + 0][srow] = ra0.x; As[skc + 1][srow] = ra0.y;
        As[skc + 2][srow] = ra0.z; As[skc + 3][srow] = ra0.w;
        As[skc + 4][srow] = ra1.x; As[skc + 5][srow] = ra1.y;
        As[skc + 6][srow] = ra1.z; As[skc + 7][srow] = ra1.w;
        Bs[skc + 0][srow] = rb0.x; Bs[skc + 1][srow] = rb0.y;
        Bs[skc + 2][srow] = rb0.z; Bs[skc + 3][srow] = rb0.w;
        Bs[skc + 4][srow] = rb1.x; Bs[skc + 5][srow] = rb1.y;
        Bs[skc + 6][srow] = rb1.z; Bs[skc + 7][srow] = rb1.w;
        __syncthreads();
        if (kt + 32 < D_) {
            ra0 = *(const float4*)(Ap + kt + 32);
            ra1 = *(const float4*)(Ap + kt + 36);
            rb0 = *(const float4*)(Bp + kt + 32);
            rb1 = *(const float4*)(Bp + kt + 36);
        }
#pragma unroll
        for (int k = 0; k < 32; ++k) {
            float4 af = *(const float4*)&As[k][m1];
            float4 bf = *(const float4*)&Bs[k][n1];
            float a[4] = {af.x, af.y, af.z, af.w};
            float b[4] = {bf.x, bf.y, bf.z, bf.w};
#pragma unroll
            for (int i = 0; i < 4; ++i)
#pragma unroll
                for (int j = 0; j < 4; ++j) acc[i][j] += a[i] * b[j];
        }
    }
#pragma unroll
    for (int i = 0; i < 4; ++i) {
        float4 v = make_float4(acc[i][0], acc[i][1], acc[i][2], acc[i][3]);
        *(float4*)&Cq[(size_t)(m0 + m1 + i) * D_ + n0 + n1] = v;
    }
}

// ---------------------------------------------------------------------------
// attention: one block per batch row. scores -> softmax -> weighted sum
// ---------------------------------------------------------------------------
__global__ __launch_bounds__(256) void k_attn(const float* __restrict__ ctx,
                                              const int* __restrict__ counts,
                                              const float* __restrict__ q,
                                              float* __restrict__ ctxv) {
    __shared__ float w_lds[C_];
    __shared__ float redm[4];
    __shared__ float reds[4];
    int b = blockIdx.x;
    int t = threadIdx.x;
    int lane = t & 63;
    int wv = t >> 6;
    int cnt = counts[b];
    const float* cb = ctx + (size_t)b * C_ * D_;

    float4 q0 = *(const float4*)&q[(size_t)b * D_ + lane * 4];
    float4 q1 = *(const float4*)&q[(size_t)b * D_ + lane * 4 + 256];

    for (int cc = wv; cc < cnt; cc += 4) {
        const float* row = cb + (size_t)cc * D_;
        float4 x0 = *(const float4*)&row[lane * 4];
        float4 x1 = *(const float4*)&row[lane * 4 + 256];
        float s = x0.x * q0.x + x0.y * q0.y + x0.z * q0.z + x0.w * q0.w +
                  x1.x * q1.x + x1.y * q1.y + x1.z * q1.z + x1.w * q1.w;
#pragma unroll
        for (int off = 32; off; off >>= 1) s += __shfl_down(s, off);
        if (lane == 0) w_lds[cc] = s;
    }
    __syncthreads();

    float sv = (t < cnt) ? w_lds[t] : -INFINITY;
    float m = sv;
#pragma unroll
    for (int off = 32; off; off >>= 1) m = fmaxf(m, __shfl_xor(m, off));
    if (lane == 0) redm[wv] = m;
    __syncthreads();
    m = fmaxf(fmaxf(redm[0], redm[1]), fmaxf(redm[2], redm[3]));
    float e = (t < cnt) ? expf(sv - m) : 0.0f;
    float ps = e;
#pragma unroll
    for (int off = 32; off; off >>= 1) ps += __shfl_xor(ps, off);
    if (lane == 0) reds[wv] = ps;
    if (t < cnt) w_lds[t] = e;
    __syncthreads();
    float inv = 1.0f / (reds[0] + reds[1] + reds[2] + reds[3]);

    float a0 = 0.f, a1 = 0.f;
#pragma unroll 4
    for (int cc = 0; cc < cnt; ++cc) {
        float wc = w_lds[cc];
        a0 += wc * cb[(size_t)cc * D_ + t];
        a1 += wc * cb[(size_t)cc * D_ + t + 256];
    }
    ctxv[(size_t)b * D_ + t] = a0 * inv;
    ctxv[(size_t)b * D_ + t + 256] = a1 * inv;
}

// ---------------------------------------------------------------------------
// gates GEMM + fused LSTM cell. 32M x 64N, BK=32, 2x4/thread, pipelined.
// grid = (2048/64, 512/32) = (32, 16) = 512 blocks.
// A[b,k]: k<256 -> emb[tok[b]][k]; k<768 -> ctxv[b,k-256]; else h_in[b,k-768]
// B tile col r -> orig gate row go = (r&3)*512 + (r>>2)  (gate order i,f,g,o)
// ---------------------------------------------------------------------------
__device__ __forceinline__ float4 gA(int arow, int atok, int kk,
                                     const float* __restrict__ emb,
                                     const float* __restrict__ ctxv,
                                     const float* __restrict__ h_in) {
    if (kk < 256) return *(const float4*)&emb[(size_t)atok * E_ + kk];
    if (kk < 768) return *(const float4*)&ctxv[(size_t)arow * D_ + kk - 256];
    return *(const float4*)&h_in[(size_t)arow * D_ + kk - 768];
}
__device__ __forceinline__ float4 gB(int go, int kk,
                                     const float* __restrict__ W_ih,
                                     const float* __restrict__ W_hh) {
    if (kk < 768) return *(const float4*)&W_ih[(size_t)go * 768 + kk];
    return *(const float4*)&W_hh[(size_t)go * D_ + kk - 768];
}

__global__ __launch_bounds__(256, 2) void k_gates(const int* __restrict__ tok,
                                                  const float* __restrict__ emb,
                                                  const float* __restrict__ ctxv,
                                                  const float* __restrict__ h_in,
                                                  const float* __restrict__ W_ih,
                                                  const float* __restrict__ b_ih,
                                                  const float* __restrict__ W_hh,
                                                  const float* __restrict__ b_hh,
                                                  float* __restrict__ cbuf,
                                                  float* __restrict__ h_out) {
    __shared__ float As[32][32];
    __shared__ float Bs[32][64];
    int t = threadIdx.x;
    int m0 = blockIdx.y * 32;
    int n0 = blockIdx.x * 64;
    int m1 = (t & 15) * 2;
    int n1 = (t >> 4) * 4;
    int asrow = t & 31, askc = (t >> 5) * 4;          // 1 float4
    int bsrow = t & 63, bskc = (t >> 6) * 8;          // 2 float4
    int arow = m0 + asrow;
    int atok = tok[arow];
    int r = n0 + bsrow;
    int go = ((r & 3) << 9) + (r >> 2);

    float4 ra = gA(arow, atok, askc, emb, ctxv, h_in);
    float4 rb0 = gB(go, bskc, W_ih, W_hh);
    float4 rb1 = gB(go, bskc + 4, W_ih, W_hh);

    float acc[2][4] = {};
    for (int kt = 0; kt < 1280; kt += 32) {
        __syncthreads();
        As[askc + 0][asrow] = ra.x; As[askc + 1][asrow] = ra.y;
        As[askc + 2][asrow] = ra.z; As[askc + 3][asrow] = ra.w;
        Bs[bskc + 0][bsrow] = rb0.x; Bs[bskc + 1][bsrow] = rb0.y;
        Bs[bskc + 2][bsrow] = rb0.z; Bs[bskc + 3][bsrow] = rb0.w;
        Bs[bskc + 4][bsrow] = rb1.x; Bs[bskc + 5][bsrow] = rb1.y;
        Bs[bskc + 6][bsrow] = rb1.z; Bs[bskc + 7][bsrow] = rb1.w;
        __syncthreads();
        if (kt + 32 < 1280) {
            ra = gA(arow, atok, kt + 32 + askc, emb, ctxv, h_in);
            rb0 = gB(go, kt + 32 + bskc, W_ih, W_hh);
            rb1 = gB(go, kt + 36 + bskc, W_ih, W_hh);
        }
#pragma unroll
        for (int k = 0; k < 32; ++k) {
            float2 af = *(const float2*)&As[k][m1];
            float4 bf = *(const float4*)&Bs[k][n1];
            float a[2] = {af.x, af.y};
            float b[4] = {bf.x, bf.y, bf.z, bf.w};
#pragma unroll
            for (int i = 0; i < 2; ++i)
#pragma unroll
                for (int j = 0; j < 4; ++j) acc[i][j] += a[i] * b[j];
        }
    }
    int d = (n0 + n1) >> 2;
    float bi = b_ih[d] + b_hh[d];
    float bf_ = b_ih[512 + d] + b_hh[512 + d];
    float bg = b_ih[1024 + d] + b_hh[1024 + d];
    float bo = b_ih[1536 + d] + b_hh[1536 + d];
#pragma unroll
    for (int i = 0; i < 2; ++i) {
        int b = m0 + m1 + i;
        float ig = sigm(acc[i][0] + bi);
        float fg = sigm(acc[i][1] + bf_);
        float gg = tanhf(acc[i][2] + bg);
        float og = sigm(acc[i][3] + bo);
        float cn = fg * cbuf[(size_t)b * D_ + d] + ig * gg;
        cbuf[(size_t)b * D_ + d] = cn;
        h_out[(size_t)b * D_ + d] = og * tanhf(cn);
    }
}

// ---------------------------------------------------------------------------
// argmax over V per batch row; first-index tie-break (matches jnp.argmax)
// ---------------------------------------------------------------------------
__global__ __launch_bounds__(256) void k_argmax(const float* __restrict__ logits,
                                                int* __restrict__ tok) {
    __shared__ float rv[4];
    __shared__ int ri[4];
    int b = blockIdx.x;
    int t = threadIdx.x;
    int lane = t & 63;
    int wv = t >> 6;
    const float* p = logits + (size_t)b * V_;
    float best = -INFINITY;
    int bi = 0x7fffffff;
    for (int v = t; v < V_; v += 256) {
        float x = p[v];
        if (x > best) { best = x; bi = v; }
    }
#pragma unroll
    for (int off = 32; off; off >>= 1) {
        float ov = __shfl_down(best, off);
        int oi = __shfl_down(bi, off);
        if (ov > best || (ov == best && oi < bi)) { best = ov; bi = oi; }
    }
    if (lane == 0) { rv[wv] = best; ri[wv] = bi; }
    __syncthreads();
    if (t == 0) {
        for (int w = 1; w < 4; ++w) {
            if (rv[w] > best || (rv[w] == best && ri[w] < bi)) { best = rv[w]; bi = ri[w]; }
        }
        tok[b] = bi;
    }
}

// ---------------------------------------------------------------------------
extern "C" void kernel_launch(void* const* d_in, const int* in_sizes, int n_in,
                              void* d_out, int out_size, void* d_ws, size_t ws_size,
                              hipStream_t stream) {
    const float* ctx    = (const float*)d_in[0];
    const int*   counts = (const int*)d_in[1];
    const float* emb    = (const float*)d_in[3];
    const float* W_attn = (const float*)d_in[4];
    const float* W_ih   = (const float*)d_in[5];
    const float* b_ih   = (const float*)d_in[6];
    const float* W_hh   = (const float*)d_in[7];
    const float* b_hh   = (const float*)d_in[8];
    const float* W_proj = (const float*)d_in[9];
    const float* b_proj = (const float*)d_in[10];
    float* out = (float*)d_out;

    float* hA   = (float*)d_ws;            // [B,D]
    float* hB   = hA + B_ * D_;            // [B,D]
    float* cbuf = hB + B_ * D_;            // [B,D]
    float* qbuf = cbuf + B_ * D_;          // [B,D]
    float* ctxv = qbuf + B_ * D_;          // [B,D]
    int*   tok  = (int*)(ctxv + B_ * D_);  // [B]

    hipMemsetAsync(out, 0, (size_t)B_ * V_ * sizeof(float), stream);

    k_init<<<B_, 256, 0, stream>>>(ctx, counts, hA, cbuf, tok);

    float* hin = hA;
    float* hout = hB;
    for (int t = 1; t < L_; ++t) {
        k_qproj<<<dim3(D_ / 64, B_ / 64), 256, 0, stream>>>(hin, W_attn, qbuf);
        k_attn<<<B_, 256, 0, stream>>>(ctx, counts, qbuf, ctxv);
        k_gates<<<dim3(G_ / 64, B_ / 32), 256, 0, stream>>>(tok, emb, ctxv, hin,
                                                            W_ih, b_ih, W_hh, b_hh,
                                                            cbuf, hout);
        float* slab = out + (size_t)t * B_ * V_;
        k_logits<<<dim3(V_ / 128, B_ / 64), 256, 0, stream>>>(hout, W_proj, b_proj, slab);
        if (t < L_ - 1) k_argmax<<<B_, 256, 0, stream>>>(slab, tok);
        float* tmp = hin; hin = hout; hout = tmp;
    }
}

// Round 4
// 2102.797 us; speedup vs baseline: 1.9870x; 1.6957x over previous
//
#include <hip/hip_runtime.h>
#include <math.h>

#define B_ 512
#define C_ 200
#define D_ 512
#define E_ 256
#define V_ 8192
#define G_ 2048
#define L_ 16

typedef __attribute__((ext_vector_type(8))) short short8;
typedef __attribute__((ext_vector_type(4))) float f32x4;

__device__ __forceinline__ float sigm(float x) { return 1.0f / (1.0f + expf(-x)); }

__device__ __forceinline__ unsigned short bf16_rn(float x) {
    unsigned int u = __float_as_uint(x);
    return (unsigned short)((u + 0x7FFFu + ((u >> 16) & 1u)) >> 16);
}
__device__ __forceinline__ float bf16f(unsigned short h) {
    return __uint_as_float(((unsigned int)h) << 16);
}

// ---------------------------------------------------------------------------
// fp32 -> (hi, lo) bf16 planes, 4 elements per thread
// ---------------------------------------------------------------------------
__global__ __launch_bounds__(256) void k_cvt(const float* __restrict__ src,
                                             unsigned short* __restrict__ hi,
                                             unsigned short* __restrict__ lo,
                                             int n4) {
    int i = blockIdx.x * 256 + threadIdx.x;
    if (i >= n4) return;
    float4 v = ((const float4*)src)[i];
    ushort4 h, l;
    h.x = bf16_rn(v.x); l.x = bf16_rn(v.x - bf16f(h.x));
    h.y = bf16_rn(v.y); l.y = bf16_rn(v.y - bf16f(h.y));
    h.z = bf16_rn(v.z); l.z = bf16_rn(v.z - bf16f(h.z));
    h.w = bf16_rn(v.w); l.w = bf16_rn(v.w - bf16f(h.w));
    ((ushort4*)hi)[i] = h;
    ((ushort4*)lo)[i] = l;
}

// ---------------------------------------------------------------------------
// Build gate-interleaved weight Wg[2048][1280]: row r -> orig gate row
// go = (r&3)*512 + (r>>2); cols [0,768) from W_ih, [768,1280) from W_hh.
// ---------------------------------------------------------------------------
__global__ __launch_bounds__(256) void k_cvt_gates(const float* __restrict__ W_ih,
                                                   const float* __restrict__ W_hh,
                                                   unsigned short* __restrict__ hi,
                                                   unsigned short* __restrict__ lo) {
    int idx = blockIdx.x * 256 + threadIdx.x;   // 2048*320 = 655360
    int r = idx / 320;
    int kq = idx - r * 320;
    int k = kq * 4;
    int go = ((r & 3) << 9) + (r >> 2);
    float4 v = (k < 768) ? *(const float4*)&W_ih[(size_t)go * 768 + k]
                         : *(const float4*)&W_hh[(size_t)go * 512 + (k - 768)];
    ushort4 h, l;
    h.x = bf16_rn(v.x); l.x = bf16_rn(v.x - bf16f(h.x));
    h.y = bf16_rn(v.y); l.y = bf16_rn(v.y - bf16f(h.y));
    h.z = bf16_rn(v.z); l.z = bf16_rn(v.z - bf16f(h.z));
    h.w = bf16_rn(v.w); l.w = bf16_rn(v.w - bf16f(h.w));
    *(ushort4*)&hi[(size_t)r * 1280 + k] = h;
    *(ushort4*)&lo[(size_t)r * 1280 + k] = l;
}

// ---------------------------------------------------------------------------
// init: h0 = c0 = mean over valid context rows (h as hi/lo bf16); tok0 = 1
// ---------------------------------------------------------------------------
__global__ __launch_bounds__(256) void k_init(const float* __restrict__ ctx,
                                              const int* __restrict__ counts,
                                              unsigned short* __restrict__ h_hi,
                                              unsigned short* __restrict__ h_lo,
                                              float* __restrict__ c,
                                              int* __restrict__ tok) {
    int b = blockIdx.x;
    int t = threadIdx.x;
    int cnt = counts[b];
    const float* base = ctx + (size_t)b * C_ * D_;
    float s0 = 0.f, s1 = 0.f;
    for (int cc = 0; cc < cnt; ++cc) {
        s0 += base[(size_t)cc * D_ + t];
        s1 += base[(size_t)cc * D_ + t + 256];
    }
    float inv = 1.0f / (float)cnt;
    float v0 = s0 * inv, v1 = s1 * inv;
    c[b * D_ + t] = v0;       c[b * D_ + t + 256] = v1;
    unsigned short p0 = bf16_rn(v0), p1 = bf16_rn(v1);
    h_hi[b * D_ + t] = p0;    h_hi[b * D_ + t + 256] = p1;
    h_lo[b * D_ + t] = bf16_rn(v0 - bf16f(p0));
    h_lo[b * D_ + t + 256] = bf16_rn(v1 - bf16f(p1));
    if (t == 0) tok[b] = 1;
}

// ---------------------------------------------------------------------------
// Split-bf16 MFMA GEMM: C[M,N] = A[M,512] @ B[N,512]^T (+bias)
// Block: 64m x 128n, 4 waves (2x2), wave tile 32x64. K_STEP=32.
// LDS fragment-canonical: slot = tile*2+plane, lane frag at slot*512+l*8.
// ---------------------------------------------------------------------------
template<bool BIAS>
__global__ __launch_bounds__(256, 2) void k_gemm(const unsigned short* __restrict__ Ah,
                                                 const unsigned short* __restrict__ Al,
                                                 const unsigned short* __restrict__ Bh,
                                                 const unsigned short* __restrict__ Bl,
                                                 const float* __restrict__ bias,
                                                 float* __restrict__ C, int ldc) {
    __shared__ short As[8 * 512];
    __shared__ short Bs[16 * 512];
    int t = threadIdx.x;
    int l = t & 63;
    int w = t >> 6;           // wave id == staging group
    int m0 = blockIdx.y * 64;
    int n0 = blockIdx.x * 128;
    int srow = l & 15;
    int koct = 8 * (l >> 4);
    int pl = w & 1;
    int mtA = w >> 1;
    const unsigned short* Apl = pl ? Al : Ah;
    const unsigned short* Bpl = pl ? Bl : Bh;
    const unsigned short* ApA = Apl + (size_t)(m0 + mtA * 16 + srow) * 512 + koct;
    const unsigned short* ApB = ApA + 32 * 512;
    const unsigned short* Bp0 = Bpl + (size_t)(n0 + (w >> 1) * 16 + srow) * 512 + koct;

    short8 rA0, rA1, rB0, rB1, rB2, rB3;
    rA0 = *(const short8*)(ApA);
    rA1 = *(const short8*)(ApB);
    rB0 = *(const short8*)(Bp0);
    rB1 = *(const short8*)(Bp0 + 32 * 512);
    rB2 = *(const short8*)(Bp0 + 64 * 512);
    rB3 = *(const short8*)(Bp0 + 96 * 512);

    f32x4 z = {0.f, 0.f, 0.f, 0.f};
    f32x4 acc[2][4];
#pragma unroll
    for (int i = 0; i < 2; ++i)
#pragma unroll
        for (int j = 0; j < 4; ++j) acc[i][j] = z;

    int wm = w >> 1, wn = w & 1;
    for (int kt = 0; kt < 512; kt += 32) {
        __syncthreads();
        *(short8*)&As[(w)*512 + l * 8] = rA0;
        *(short8*)&As[(w + 4) * 512 + l * 8] = rA1;
        *(short8*)&Bs[(w)*512 + l * 8] = rB0;
        *(short8*)&Bs[(w + 4) * 512 + l * 8] = rB1;
        *(short8*)&Bs[(w + 8) * 512 + l * 8] = rB2;
        *(short8*)&Bs[(w + 12) * 512 + l * 8] = rB3;
        __syncthreads();
        if (kt + 32 < 512) {
            rA0 = *(const short8*)(ApA + kt + 32);
            rA1 = *(const short8*)(ApB + kt + 32);
            rB0 = *(const short8*)(Bp0 + kt + 32);
            rB1 = *(const short8*)(Bp0 + 32 * 512 + kt + 32);
            rB2 = *(const short8*)(Bp0 + 64 * 512 + kt + 32);
            rB3 = *(const short8*)(Bp0 + 96 * 512 + kt + 32);
        }
        short8 ah[2], al2[2], bh[4], bl2[4];
#pragma unroll
        for (int i = 0; i < 2; ++i) {
            ah[i] = *(short8*)&As[((wm * 2 + i) * 2 + 0) * 512 + l * 8];
            al2[i] = *(short8*)&As[((wm * 2 + i) * 2 + 1) * 512 + l * 8];
        }
#pragma unroll
        for (int j = 0; j < 4; ++j) {
            bh[j] = *(short8*)&Bs[((wn * 4 + j) * 2 + 0) * 512 + l * 8];
            bl2[j] = *(short8*)&Bs[((wn * 4 + j) * 2 + 1) * 512 + l * 8];
        }
#pragma unroll
        for (int i = 0; i < 2; ++i)
#pragma unroll
            for (int j = 0; j < 4; ++j) {
                acc[i][j] = __builtin_amdgcn_mfma_f32_16x16x32_bf16(ah[i], bh[j], acc[i][j], 0, 0, 0);
                acc[i][j] = __builtin_amdgcn_mfma_f32_16x16x32_bf16(ah[i], bl2[j], acc[i][j], 0, 0, 0);
                acc[i][j] = __builtin_amdgcn_mfma_f32_16x16x32_bf16(al2[i], bh[j], acc[i][j], 0, 0, 0);
            }
    }
    int r0 = (l >> 4) * 4;
    int cl = l & 15;
#pragma unroll
    for (int i = 0; i < 2; ++i)
#pragma unroll
        for (int j = 0; j < 4; ++j) {
            int col = n0 + wn * 64 + j * 16 + cl;
            float bj = BIAS ? bias[col] : 0.f;
            int rowb = m0 + wm * 32 + i * 16 + r0;
#pragma unroll
            for (int r = 0; r < 4; ++r)
                C[(size_t)(rowb + r) * ldc + col] = acc[i][j][r] + bj;
        }
}

// ---------------------------------------------------------------------------
// attention: one block per batch row; epilogue emits ctxv as hi/lo bf16
// ---------------------------------------------------------------------------
__global__ __launch_bounds__(256) void k_attn(const float* __restrict__ ctx,
                                              const int* __restrict__ counts,
                                              const float* __restrict__ q,
                                              unsigned short* __restrict__ cv_hi,
                                              unsigned short* __restrict__ cv_lo) {
    __shared__ float w_lds[C_];
    __shared__ float redm[4];
    __shared__ float reds[4];
    int b = blockIdx.x;
    int t = threadIdx.x;
    int lane = t & 63;
    int wv = t >> 6;
    int cnt = counts[b];
    const float* cb = ctx + (size_t)b * C_ * D_;

    float4 q0 = *(const float4*)&q[(size_t)b * D_ + lane * 4];
    float4 q1 = *(const float4*)&q[(size_t)b * D_ + lane * 4 + 256];

    for (int cc = wv; cc < cnt; cc += 4) {
        const float* row = cb + (size_t)cc * D_;
        float4 x0 = *(const float4*)&row[lane * 4];
        float4 x1 = *(const float4*)&row[lane * 4 + 256];
        float s = x0.x * q0.x + x0.y * q0.y + x0.z * q0.z + x0.w * q0.w +
                  x1.x * q1.x + x1.y * q1.y + x1.z * q1.z + x1.w * q1.w;
#pragma unroll
        for (int off = 32; off; off >>= 1) s += __shfl_down(s, off);
        if (lane == 0) w_lds[cc] = s;
    }
    __syncthreads();

    float sv = (t < cnt) ? w_lds[t] : -INFINITY;
    float m = sv;
#pragma unroll
    for (int off = 32; off; off >>= 1) m = fmaxf(m, __shfl_xor(m, off));
    if (lane == 0) redm[wv] = m;
    __syncthreads();
    m = fmaxf(fmaxf(redm[0], redm[1]), fmaxf(redm[2], redm[3]));
    float e = (t < cnt) ? expf(sv - m) : 0.0f;
    float ps = e;
#pragma unroll
    for (int off = 32; off; off >>= 1) ps += __shfl_xor(ps, off);
    if (lane == 0) reds[wv] = ps;
    if (t < cnt) w_lds[t] = e;
    __syncthreads();
    float inv = 1.0f / (reds[0] + reds[1] + reds[2] + reds[3]);

    float a0 = 0.f, a1 = 0.f;
#pragma unroll 4
    for (int cc = 0; cc < cnt; ++cc) {
        float wc = w_lds[cc];
        a0 += wc * cb[(size_t)cc * D_ + t];
        a1 += wc * cb[(size_t)cc * D_ + t + 256];
    }
    float v0 = a0 * inv, v1 = a1 * inv;
    unsigned short p0 = bf16_rn(v0), p1 = bf16_rn(v1);
    cv_hi[(size_t)b * D_ + t] = p0;
    cv_hi[(size_t)b * D_ + t + 256] = p1;
    cv_lo[(size_t)b * D_ + t] = bf16_rn(v0 - bf16f(p0));
    cv_lo[(size_t)b * D_ + t + 256] = bf16_rn(v1 - bf16f(p1));
}

// ---------------------------------------------------------------------------
// gates GEMM (split-bf16 MFMA, K=1280) + fused LSTM epilogue.
// Block 64m x 64n, 4 waves (2x2), wave tile 32x32.
// A: k<256 emb[tok], k<768 ctxv, else h. B: Wg (gate-interleaved cols).
// ---------------------------------------------------------------------------
__global__ __launch_bounds__(256, 2) void k_gatesm(const int* __restrict__ tok,
                                                   const unsigned short* __restrict__ Eh,
                                                   const unsigned short* __restrict__ El,
                                                   const unsigned short* __restrict__ Ch,
                                                   const unsigned short* __restrict__ Cl,
                                                   const unsigned short* __restrict__ Hh,
                                                   const unsigned short* __restrict__ Hl,
                                                   const unsigned short* __restrict__ Wh,
                                                   const unsigned short* __restrict__ Wl,
                                                   const float* __restrict__ b_ih,
                                                   const float* __restrict__ b_hh,
                                                   float* __restrict__ cbuf,
                                                   unsigned short* __restrict__ Hoh,
                                                   unsigned short* __restrict__ Hol) {
    __shared__ short As[8 * 512];
    __shared__ short Bs[8 * 512];
    int t = threadIdx.x;
    int l = t & 63;
    int w = t >> 6;
    int m0 = blockIdx.y * 64;
    int n0 = blockIdx.x * 64;
    int srow = l & 15;
    int koct = 8 * (l >> 4);
    int pl = w & 1;
    int mtA = w >> 1;
    int rowA = m0 + mtA * 16 + srow;
    int rowB = rowA + 32;
    int tokA = tok[rowA];
    int tokB = tok[rowB];
    const unsigned short* Ep = pl ? El : Eh;
    const unsigned short* Cp = pl ? Cl : Ch;
    const unsigned short* Hp = pl ? Hl : Hh;
    const unsigned short* Wp = pl ? Wl : Wh;
    const unsigned short* Wp0 = Wp + (size_t)(n0 + (w >> 1) * 16 + srow) * 1280 + koct;

    f32x4 z = {0.f, 0.f, 0.f, 0.f};
    f32x4 acc[2][2];
#pragma unroll
    for (int i = 0; i < 2; ++i)
#pragma unroll
        for (int j = 0; j < 2; ++j) acc[i][j] = z;

    int wm = w >> 1, wn = w & 1;
    short8 rA0, rA1, rB0, rB1;

#define GATES_LOADA(dst, row, tk, kk)                                          \
    {                                                                          \
        int kx = (kk);                                                         \
        if (kx < 256)      dst = *(const short8*)&Ep[(size_t)(tk)*256 + kx];   \
        else if (kx < 768) dst = *(const short8*)&Cp[(size_t)(row)*512 + (kx - 256)]; \
        else               dst = *(const short8*)&Hp[(size_t)(row)*512 + (kx - 768)]; \
    }

    GATES_LOADA(rA0, rowA, tokA, koct);
    GATES_LOADA(rA1, rowB, tokB, koct);
    rB0 = *(const short8*)(Wp0);
    rB1 = *(const short8*)(Wp0 + 32 * 1280);

    for (int kt = 0; kt < 1280; kt += 32) {
        __syncthreads();
        *(short8*)&As[(w)*512 + l * 8] = rA0;
        *(short8*)&As[(w + 4) * 512 + l * 8] = rA1;
        *(short8*)&Bs[(w)*512 + l * 8] = rB0;
        *(short8*)&Bs[(w + 4) * 512 + l * 8] = rB1;
        __syncthreads();
        if (kt + 32 < 1280) {
            GATES_LOADA(rA0, rowA, tokA, kt + 32 + koct);
            GATES_LOADA(rA1, rowB, tokB, kt + 32 + koct);
            rB0 = *(const short8*)(Wp0 + kt + 32);
            rB1 = *(const short8*)(Wp0 + 32 * 1280 + kt + 32);
        }
        short8 ah[2], al2[2], bh[2], bl2[2];
#pragma unroll
        for (int i = 0; i < 2; ++i) {
            ah[i] = *(short8*)&As[((wm * 2 + i) * 2 + 0) * 512 + l * 8];
            al2[i] = *(short8*)&As[((wm * 2 + i) * 2 + 1) * 512 + l * 8];
        }
#pragma unroll
        for (int j = 0; j < 2; ++j) {
            bh[j] = *(short8*)&Bs[((wn * 2 + j) * 2 + 0) * 512 + l * 8];
            bl2[j] = *(short8*)&Bs[((wn * 2 + j) * 2 + 1) * 512 + l * 8];
        }
#pragma unroll
        for (int i = 0; i < 2; ++i)
#pragma unroll
            for (int j = 0; j < 2; ++j) {
                acc[i][j] = __builtin_amdgcn_mfma_f32_16x16x32_bf16(ah[i], bh[j], acc[i][j], 0, 0, 0);
                acc[i][j] = __builtin_amdgcn_mfma_f32_16x16x32_bf16(ah[i], bl2[j], acc[i][j], 0, 0, 0);
                acc[i][j] = __builtin_amdgcn_mfma_f32_16x16x32_bf16(al2[i], bh[j], acc[i][j], 0, 0, 0);
            }
    }

    // LSTM epilogue: col gc -> gate gc&3 of d = gc>>2; lanes (cl&3)==0 own d.
    int r0 = (l >> 4) * 4;
    int cl = l & 15;
    bool act = (cl & 3) == 0;
#pragma unroll
    for (int j = 0; j < 2; ++j) {
        int gc = n0 + wn * 32 + j * 16 + cl;
        int d = gc >> 2;
        float bi_ = b_ih[d] + b_hh[d];
        float bf_ = b_ih[512 + d] + b_hh[512 + d];
        float bg_ = b_ih[1024 + d] + b_hh[1024 + d];
        float bo_ = b_ih[1536 + d] + b_hh[1536 + d];
#pragma unroll
        for (int i = 0; i < 2; ++i) {
#pragma unroll
            for (int r = 0; r < 4; ++r) {
                float x = acc[i][j][r];
                float x1 = __shfl_xor(x, 1);
                float x2 = __shfl_xor(x, 2);
                float x3 = __shfl_xor(x, 3);
                if (act) {
                    int row = m0 + wm * 32 + i * 16 + r0 + r;
                    float ig = sigm(x + bi_);
                    float fg = sigm(x1 + bf_);
                    float gg = tanhf(x2 + bg_);
                    float og = sigm(x3 + bo_);
                    float cn = fg * cbuf[(size_t)row * D_ + d] + ig * gg;
                    cbuf[(size_t)row * D_ + d] = cn;
                    float hv = og * tanhf(cn);
                    unsigned short hh = bf16_rn(hv);
                    Hoh[(size_t)row * D_ + d] = hh;
                    Hol[(size_t)row * D_ + d] = bf16_rn(hv - bf16f(hh));
                }
            }
        }
    }
}

// ---------------------------------------------------------------------------
// argmax over V per batch row; first-index tie-break
// ---------------------------------------------------------------------------
__global__ __launch_bounds__(256) void k_argmax(const float* __restrict__ logits,
                                                int* __restrict__ tok) {
    __shared__ float rv[4];
    __shared__ int ri[4];
    int b = blockIdx.x;
    int t = threadIdx.x;
    int lane = t & 63;
    int wv = t >> 6;
    const float* p = logits + (size_t)b * V_;
    float best = -INFINITY;
    int bi = 0x7fffffff;
    for (int v = t; v < V_; v += 256) {
        float x = p[v];
        if (x > best) { best = x; bi = v; }
    }
#pragma unroll
    for (int off = 32; off; off >>= 1) {
        float ov = __shfl_down(best, off);
        int oi = __shfl_down(bi, off);
        if (ov > best || (ov == best && oi < bi)) { best = ov; bi = oi; }
    }
    if (lane == 0) { rv[wv] = best; ri[wv] = bi; }
    __syncthreads();
    if (t == 0) {
        for (int w = 1; w < 4; ++w) {
            if (rv[w] > best || (rv[w] == best && ri[w] < bi)) { best = rv[w]; bi = ri[w]; }
        }
        tok[b] = bi;
    }
}

// ---------------------------------------------------------------------------
extern "C" void kernel_launch(void* const* d_in, const int* in_sizes, int n_in,
                              void* d_out, int out_size, void* d_ws, size_t ws_size,
                              hipStream_t stream) {
    const float* ctx    = (const float*)d_in[0];
    const int*   counts = (const int*)d_in[1];
    const float* emb    = (const float*)d_in[3];
    const float* W_attn = (const float*)d_in[4];
    const float* W_ih   = (const float*)d_in[5];
    const float* b_ih   = (const float*)d_in[6];
    const float* W_hh   = (const float*)d_in[7];
    const float* b_hh   = (const float*)d_in[8];
    const float* W_proj = (const float*)d_in[9];
    const float* b_proj = (const float*)d_in[10];
    float* out = (float*)d_out;

    // fp32 scratch
    float* qbuf = (float*)d_ws;                 // [512][512]
    float* cbuf = qbuf + B_ * D_;               // [512][512]
    unsigned short* p = (unsigned short*)(cbuf + B_ * D_);
    unsigned short* Wa_hi = p; p += D_ * D_;
    unsigned short* Wa_lo = p; p += D_ * D_;
    unsigned short* Wp_hi = p; p += (size_t)V_ * D_;
    unsigned short* Wp_lo = p; p += (size_t)V_ * D_;
    unsigned short* Eb_hi = p; p += (size_t)V_ * E_;
    unsigned short* Eb_lo = p; p += (size_t)V_ * E_;
    unsigned short* Wg_hi = p; p += (size_t)G_ * 1280;
    unsigned short* Wg_lo = p; p += (size_t)G_ * 1280;
    unsigned short* hA_hi = p; p += B_ * D_;
    unsigned short* hA_lo = p; p += B_ * D_;
    unsigned short* hB_hi = p; p += B_ * D_;
    unsigned short* hB_lo = p; p += B_ * D_;
    unsigned short* cv_hi = p; p += B_ * D_;
    unsigned short* cv_lo = p; p += B_ * D_;
    int* tok = (int*)p;                         // [512]

    // one-time (per call) weight/emb conversions
    k_cvt<<<256, 256, 0, stream>>>(W_attn, Wa_hi, Wa_lo, D_ * D_ / 4);
    k_cvt<<<4096, 256, 0, stream>>>(W_proj, Wp_hi, Wp_lo, V_ * D_ / 4);
    k_cvt<<<2048, 256, 0, stream>>>(emb, Eb_hi, Eb_lo, V_ * E_ / 4);
    k_cvt_gates<<<2560, 256, 0, stream>>>(W_ih, W_hh, Wg_hi, Wg_lo);

    hipMemsetAsync(out, 0, (size_t)B_ * V_ * sizeof(float), stream);

    k_init<<<B_, 256, 0, stream>>>(ctx, counts, hA_hi, hA_lo, cbuf, tok);

    unsigned short *hin_hi = hA_hi, *hin_lo = hA_lo;
    unsigned short *hout_hi = hB_hi, *hout_lo = hB_lo;
    for (int t = 1; t < L_; ++t) {
        k_gemm<false><<<dim3(D_ / 128, B_ / 64), 256, 0, stream>>>(
            hin_hi, hin_lo, Wa_hi, Wa_lo, nullptr, qbuf, D_);
        k_attn<<<B_, 256, 0, stream>>>(ctx, counts, qbuf, cv_hi, cv_lo);
        k_gatesm<<<dim3(G_ / 64, B_ / 64), 256, 0, stream>>>(
            tok, Eb_hi, Eb_lo, cv_hi, cv_lo, hin_hi, hin_lo,
            Wg_hi, Wg_lo, b_ih, b_hh, cbuf, hout_hi, hout_lo);
        float* slab = out + (size_t)t * B_ * V_;
        k_gemm<true><<<dim3(V_ / 128, B_ / 64), 256, 0, stream>>>(
            hout_hi, hout_lo, Wp_hi, Wp_lo, b_proj, slab, V_);
        if (t < L_ - 1) k_argmax<<<B_, 256, 0, stream>>>(slab, tok);
        unsigned short* tmp;
        tmp = hin_hi; hin_hi = hout_hi; hout_hi = tmp;
        tmp = hin_lo; hin_lo = hout_lo; hout_lo = tmp;
    }
}

// Round 5
// 1797.371 us; speedup vs baseline: 2.3246x; 1.1699x over previous
//
#include <hip/hip_runtime.h>
#include <math.h>

#define B_ 512
#define C_ 200
#define D_ 512
#define E_ 256
#define V_ 8192
#define G_ 2048
#define L_ 16

typedef __attribute__((ext_vector_type(8))) short short8;
typedef __attribute__((ext_vector_type(4))) float f32x4;

__device__ __forceinline__ float sigm(float x) { return 1.0f / (1.0f + expf(-x)); }

__device__ __forceinline__ unsigned short bf16_rn(float x) {
    unsigned int u = __float_as_uint(x);
    return (unsigned short)((u + 0x7FFFu + ((u >> 16) & 1u)) >> 16);
}
__device__ __forceinline__ float bf16f(unsigned short h) {
    return __uint_as_float(((unsigned int)h) << 16);
}

// ---------------------------------------------------------------------------
// fp32 -> (hi, lo) bf16 planes, 4 elements per thread
// ---------------------------------------------------------------------------
__global__ __launch_bounds__(256) void k_cvt(const float* __restrict__ src,
                                             unsigned short* __restrict__ hi,
                                             unsigned short* __restrict__ lo,
                                             int n4) {
    int i = blockIdx.x * 256 + threadIdx.x;
    if (i >= n4) return;
    float4 v = ((const float4*)src)[i];
    ushort4 h, l;
    h.x = bf16_rn(v.x); l.x = bf16_rn(v.x - bf16f(h.x));
    h.y = bf16_rn(v.y); l.y = bf16_rn(v.y - bf16f(h.y));
    h.z = bf16_rn(v.z); l.z = bf16_rn(v.z - bf16f(h.z));
    h.w = bf16_rn(v.w); l.w = bf16_rn(v.w - bf16f(h.w));
    ((ushort4*)hi)[i] = h;
    ((ushort4*)lo)[i] = l;
}

// ---------------------------------------------------------------------------
// Build gate-interleaved weight Wg[2048][1280]: row r -> orig gate row
// go = (r&3)*512 + (r>>2); cols [0,768) from W_ih, [768,1280) from W_hh.
// ---------------------------------------------------------------------------
__global__ __launch_bounds__(256) void k_cvt_gates(const float* __restrict__ W_ih,
                                                   const float* __restrict__ W_hh,
                                                   unsigned short* __restrict__ hi,
                                                   unsigned short* __restrict__ lo) {
    int idx = blockIdx.x * 256 + threadIdx.x;   // 2048*320 = 655360
    int r = idx / 320;
    int kq = idx - r * 320;
    int k = kq * 4;
    int go = ((r & 3) << 9) + (r >> 2);
    float4 v = (k < 768) ? *(const float4*)&W_ih[(size_t)go * 768 + k]
                         : *(const float4*)&W_hh[(size_t)go * 512 + (k - 768)];
    ushort4 h, l;
    h.x = bf16_rn(v.x); l.x = bf16_rn(v.x - bf16f(h.x));
    h.y = bf16_rn(v.y); l.y = bf16_rn(v.y - bf16f(h.y));
    h.z = bf16_rn(v.z); l.z = bf16_rn(v.z - bf16f(h.z));
    h.w = bf16_rn(v.w); l.w = bf16_rn(v.w - bf16f(h.w));
    *(ushort4*)&hi[(size_t)r * 1280 + k] = h;
    *(ushort4*)&lo[(size_t)r * 1280 + k] = l;
}

// ---------------------------------------------------------------------------
// init: h0 = c0 = mean over valid context rows (h as hi/lo bf16); tok0 = 1
// ---------------------------------------------------------------------------
__global__ __launch_bounds__(256) void k_init(const float* __restrict__ ctx,
                                              const int* __restrict__ counts,
                                              unsigned short* __restrict__ h_hi,
                                              unsigned short* __restrict__ h_lo,
                                              float* __restrict__ c,
                                              int* __restrict__ tok) {
    int b = blockIdx.x;
    int t = threadIdx.x;
    int cnt = counts[b];
    const float* base = ctx + (size_t)b * C_ * D_;
    float s0 = 0.f, s1 = 0.f;
    for (int cc = 0; cc < cnt; ++cc) {
        s0 += base[(size_t)cc * D_ + t];
        s1 += base[(size_t)cc * D_ + t + 256];
    }
    float inv = 1.0f / (float)cnt;
    float v0 = s0 * inv, v1 = s1 * inv;
    c[b * D_ + t] = v0;       c[b * D_ + t + 256] = v1;
    unsigned short p0 = bf16_rn(v0), p1 = bf16_rn(v1);
    h_hi[b * D_ + t] = p0;    h_hi[b * D_ + t + 256] = p1;
    h_lo[b * D_ + t] = bf16_rn(v0 - bf16f(p0));
    h_lo[b * D_ + t + 256] = bf16_rn(v1 - bf16f(p1));
    if (t == 0) tok[b] = 1;
}

// ---------------------------------------------------------------------------
// Split-bf16 MFMA GEMM: C[M,N] = A[M,512] @ B[N,512]^T
// Block: 64m x 128n, 4 waves (2x2), wave tile 32x64. K_STEP=32.
// MODE 0: plain (qproj, no swizzle).  MODE 1: logits — XCD swizzle (grid
// fixed 64x8), +bias, + per-block argmax partials (first-index tie-break).
// ---------------------------------------------------------------------------
template<int MODE>
__global__ __launch_bounds__(256, 2) void k_gemm(const unsigned short* __restrict__ Ah,
                                                 const unsigned short* __restrict__ Al,
                                                 const unsigned short* __restrict__ Bh,
                                                 const unsigned short* __restrict__ Bl,
                                                 const float* __restrict__ bias,
                                                 float* __restrict__ C, int ldc,
                                                 float* __restrict__ pvO,
                                                 int* __restrict__ piO) {
    __shared__ short As[8 * 512];
    __shared__ short Bs[16 * 512];
    __shared__ float pvS[64][2];
    __shared__ int piS[64][2];
    int t = threadIdx.x;
    int l = t & 63;
    int w = t >> 6;           // wave id == staging group
    int nb, mb;
    if (MODE == 1) {          // grid is (64, 8); XCD-strip swizzle
        int wg = blockIdx.y * 64 + blockIdx.x;
        int xcd = wg & 7, lid = wg >> 3;
        nb = xcd * 8 + (lid & 7);
        mb = lid >> 3;
    } else {
        nb = blockIdx.x; mb = blockIdx.y;
    }
    int m0 = mb * 64;
    int n0 = nb * 128;
    int srow = l & 15;
    int koct = 8 * (l >> 4);
    int pl = w & 1;
    int mtA = w >> 1;
    const unsigned short* Apl = pl ? Al : Ah;
    const unsigned short* Bpl = pl ? Bl : Bh;
    const unsigned short* ApA = Apl + (size_t)(m0 + mtA * 16 + srow) * 512 + koct;
    const unsigned short* ApB = ApA + 32 * 512;
    const unsigned short* Bp0 = Bpl + (size_t)(n0 + (w >> 1) * 16 + srow) * 512 + koct;

    short8 rA0, rA1, rB0, rB1, rB2, rB3;
    rA0 = *(const short8*)(ApA);
    rA1 = *(const short8*)(ApB);
    rB0 = *(const short8*)(Bp0);
    rB1 = *(const short8*)(Bp0 + 32 * 512);
    rB2 = *(const short8*)(Bp0 + 64 * 512);
    rB3 = *(const short8*)(Bp0 + 96 * 512);

    f32x4 z = {0.f, 0.f, 0.f, 0.f};
    f32x4 acc[2][4];
#pragma unroll
    for (int i = 0; i < 2; ++i)
#pragma unroll
        for (int j = 0; j < 4; ++j) acc[i][j] = z;

    int wm = w >> 1, wn = w & 1;
    for (int kt = 0; kt < 512; kt += 32) {
        __syncthreads();
        *(short8*)&As[(w)*512 + l * 8] = rA0;
        *(short8*)&As[(w + 4) * 512 + l * 8] = rA1;
        *(short8*)&Bs[(w)*512 + l * 8] = rB0;
        *(short8*)&Bs[(w + 4) * 512 + l * 8] = rB1;
        *(short8*)&Bs[(w + 8) * 512 + l * 8] = rB2;
        *(short8*)&Bs[(w + 12) * 512 + l * 8] = rB3;
        __syncthreads();
        if (kt + 32 < 512) {
            rA0 = *(const short8*)(ApA + kt + 32);
            rA1 = *(const short8*)(ApB + kt + 32);
            rB0 = *(const short8*)(Bp0 + kt + 32);
            rB1 = *(const short8*)(Bp0 + 32 * 512 + kt + 32);
            rB2 = *(const short8*)(Bp0 + 64 * 512 + kt + 32);
            rB3 = *(const short8*)(Bp0 + 96 * 512 + kt + 32);
        }
        short8 ah[2], al2[2], bh[4], bl2[4];
#pragma unroll
        for (int i = 0; i < 2; ++i) {
            ah[i] = *(short8*)&As[((wm * 2 + i) * 2 + 0) * 512 + l * 8];
            al2[i] = *(short8*)&As[((wm * 2 + i) * 2 + 1) * 512 + l * 8];
        }
#pragma unroll
        for (int j = 0; j < 4; ++j) {
            bh[j] = *(short8*)&Bs[((wn * 4 + j) * 2 + 0) * 512 + l * 8];
            bl2[j] = *(short8*)&Bs[((wn * 4 + j) * 2 + 1) * 512 + l * 8];
        }
#pragma unroll
        for (int i = 0; i < 2; ++i)
#pragma unroll
            for (int j = 0; j < 4; ++j) {
                acc[i][j] = __builtin_amdgcn_mfma_f32_16x16x32_bf16(ah[i], bh[j], acc[i][j], 0, 0, 0);
                acc[i][j] = __builtin_amdgcn_mfma_f32_16x16x32_bf16(ah[i], bl2[j], acc[i][j], 0, 0, 0);
                acc[i][j] = __builtin_amdgcn_mfma_f32_16x16x32_bf16(al2[i], bh[j], acc[i][j], 0, 0, 0);
            }
    }
    int r0 = (l >> 4) * 4;
    int cl = l & 15;
    if (MODE == 1) {
        float bj_[4];
#pragma unroll
        for (int j = 0; j < 4; ++j) bj_[j] = bias[n0 + wn * 64 + j * 16 + cl];
#pragma unroll
        for (int i = 0; i < 2; ++i) {
#pragma unroll
            for (int r = 0; r < 4; ++r) {
                int row = m0 + wm * 32 + i * 16 + r0 + r;
                float bv = -INFINITY;
                int bidx = 0x7fffffff;
#pragma unroll
                for (int j = 0; j < 4; ++j) {
                    int col = n0 + wn * 64 + j * 16 + cl;
                    float v = acc[i][j][r] + bj_[j];
                    C[(size_t)row * ldc + col] = v;
                    if (v > bv) { bv = v; bidx = col; }
                }
#pragma unroll
                for (int off = 1; off < 16; off <<= 1) {
                    float ov = __shfl_xor(bv, off);
                    int oi = __shfl_xor(bidx, off);
                    if (ov > bv || (ov == bv && oi < bidx)) { bv = ov; bidx = oi; }
                }
                if (cl == 0) {
                    pvS[wm * 32 + i * 16 + r0 + r][wn] = bv;
                    piS[wm * 32 + i * 16 + r0 + r][wn] = bidx;
                }
            }
        }
        __syncthreads();
        if (t < 64) {
            float v0 = pvS[t][0], v1 = pvS[t][1];
            int i0 = piS[t][0], i1 = piS[t][1];
            bool take1 = (v1 > v0);   // tie -> slot 0 (smaller cols)
            pvO[(size_t)(m0 + t) * 64 + nb] = take1 ? v1 : v0;
            piO[(size_t)(m0 + t) * 64 + nb] = take1 ? i1 : i0;
        }
    } else {
#pragma unroll
        for (int i = 0; i < 2; ++i)
#pragma unroll
            for (int j = 0; j < 4; ++j) {
                int col = n0 + wn * 64 + j * 16 + cl;
                int rowb = m0 + wm * 32 + i * 16 + r0;
#pragma unroll
                for (int r = 0; r < 4; ++r)
                    C[(size_t)(rowb + r) * ldc + col] = acc[i][j][r];
            }
    }
}

// ---------------------------------------------------------------------------
// argmax partial reduce: tok[b] = argmax over 64 n-block partials
// ---------------------------------------------------------------------------
__global__ __launch_bounds__(64) void k_argmax_red(const float* __restrict__ pv,
                                                   const int* __restrict__ pi,
                                                   int* __restrict__ tok) {
    int b = blockIdx.x;
    int t = threadIdx.x;  // 0..63 == n-block
    float v = pv[(size_t)b * 64 + t];
    int ix = pi[(size_t)b * 64 + t];
#pragma unroll
    for (int off = 32; off; off >>= 1) {
        float ov = __shfl_xor(v, off);
        int oi = __shfl_xor(ix, off);
        if (ov > v || (ov == v && oi < ix)) { v = ov; ix = oi; }
    }
    if (t == 0) tok[b] = ix;
}

// ---------------------------------------------------------------------------
// attention: single-pass online softmax. One block per batch row, 4 waves.
// Wave w streams rows w, w+4, ... keeping running (max, sum, acc[8 dims/lane]).
// Combine across waves in LDS; epilogue emits ctxv as hi/lo bf16.
// ---------------------------------------------------------------------------
__global__ __launch_bounds__(256) void k_attn(const float* __restrict__ ctx,
                                              const int* __restrict__ counts,
                                              const float* __restrict__ q,
                                              unsigned short* __restrict__ cv_hi,
                                              unsigned short* __restrict__ cv_lo) {
    __shared__ float accw[4][512];
    __shared__ float mw_s[4], sw_s[4];
    int b = blockIdx.x;
    int t = threadIdx.x;
    int lane = t & 63;
    int wv = t >> 6;
    int cnt = counts[b];
    const float* cb = ctx + (size_t)b * C_ * D_;

    float4 q0 = *(const float4*)&q[(size_t)b * D_ + lane * 4];
    float4 q1 = *(const float4*)&q[(size_t)b * D_ + lane * 4 + 256];

    float m_w = -INFINITY, s_w = 0.f;
    float4 a0 = make_float4(0.f, 0.f, 0.f, 0.f);
    float4 a1 = make_float4(0.f, 0.f, 0.f, 0.f);

#define ATT_DOT(x0, x1) (x0.x * q0.x + x0.y * q0.y + x0.z * q0.z + x0.w * q0.w + \
                         x1.x * q1.x + x1.y * q1.y + x1.z * q1.z + x1.w * q1.w)
#define ATT_UPD(s, x0, x1)                                                     \
    {                                                                          \
        float e;                                                               \
        if (s > m_w) {                                                         \
            float sc = expf(m_w - s);                                          \
            s_w = s_w * sc + 1.f;                                              \
            a0.x *= sc; a0.y *= sc; a0.z *= sc; a0.w *= sc;                    \
            a1.x *= sc; a1.y *= sc; a1.z *= sc; a1.w *= sc;                    \
            m_w = s; e = 1.f;                                                  \
        } else {                                                               \
            e = expf(s - m_w);                                                 \
            s_w += e;                                                          \
        }                                                                      \
        a0.x += e * x0.x; a0.y += e * x0.y; a0.z += e * x0.z; a0.w += e * x0.w;\
        a1.x += e * x1.x; a1.y += e * x1.y; a1.z += e * x1.z; a1.w += e * x1.w;\
    }

    int cc = wv;
    for (; cc + 4 < cnt; cc += 8) {
        const float* rA = cb + (size_t)cc * D_;
        const float* rB = cb + (size_t)(cc + 4) * D_;
        float4 xa0 = *(const float4*)&rA[lane * 4];
        float4 xa1 = *(const float4*)&rA[lane * 4 + 256];
        float4 xb0 = *(const float4*)&rB[lane * 4];
        float4 xb1 = *(const float4*)&rB[lane * 4 + 256];
        float sa = ATT_DOT(xa0, xa1);
        float sb = ATT_DOT(xb0, xb1);
#pragma unroll
        for (int off = 32; off; off >>= 1) {
            sa += __shfl_xor(sa, off);
            sb += __shfl_xor(sb, off);
        }
        ATT_UPD(sa, xa0, xa1);
        ATT_UPD(sb, xb0, xb1);
    }
    if (cc < cnt) {
        const float* rA = cb + (size_t)cc * D_;
        float4 xa0 = *(const float4*)&rA[lane * 4];
        float4 xa1 = *(const float4*)&rA[lane * 4 + 256];
        float sa = ATT_DOT(xa0, xa1);
#pragma unroll
        for (int off = 32; off; off >>= 1) sa += __shfl_xor(sa, off);
        ATT_UPD(sa, xa0, xa1);
    }

    accw[wv][lane * 4 + 0] = a0.x; accw[wv][lane * 4 + 1] = a0.y;
    accw[wv][lane * 4 + 2] = a0.z; accw[wv][lane * 4 + 3] = a0.w;
    accw[wv][256 + lane * 4 + 0] = a1.x; accw[wv][256 + lane * 4 + 1] = a1.y;
    accw[wv][256 + lane * 4 + 2] = a1.z; accw[wv][256 + lane * 4 + 3] = a1.w;
    if (lane == 0) { mw_s[wv] = m_w; sw_s[wv] = s_w; }
    __syncthreads();

    float m_g = fmaxf(fmaxf(mw_s[0], mw_s[1]), fmaxf(mw_s[2], mw_s[3]));
    float e0 = expf(mw_s[0] - m_g), e1 = expf(mw_s[1] - m_g);
    float e2 = expf(mw_s[2] - m_g), e3 = expf(mw_s[3] - m_g);
    float inv = 1.0f / (sw_s[0] * e0 + sw_s[1] * e1 + sw_s[2] * e2 + sw_s[3] * e3);
    float v0 = (accw[0][t] * e0 + accw[1][t] * e1 + accw[2][t] * e2 + accw[3][t] * e3) * inv;
    float v1 = (accw[0][t + 256] * e0 + accw[1][t + 256] * e1 +
                accw[2][t + 256] * e2 + accw[3][t + 256] * e3) * inv;
    unsigned short p0 = bf16_rn(v0), p1 = bf16_rn(v1);
    cv_hi[(size_t)b * D_ + t] = p0;
    cv_hi[(size_t)b * D_ + t + 256] = p1;
    cv_lo[(size_t)b * D_ + t] = bf16_rn(v0 - bf16f(p0));
    cv_lo[(size_t)b * D_ + t + 256] = bf16_rn(v1 - bf16f(p1));
}

// ---------------------------------------------------------------------------
// gates GEMM (split-bf16 MFMA, K=1280) + fused LSTM epilogue.
// Block 64m x 64n, 4 waves (2x2), wave tile 32x32. Grid fixed (32, 8),
// XCD-strip swizzle (Wg strip 1.3MB -> per-XCD L2 resident).
// ---------------------------------------------------------------------------
__global__ __launch_bounds__(256, 2) void k_gatesm(const int* __restrict__ tok,
                                                   const unsigned short* __restrict__ Eh,
                                                   const unsigned short* __restrict__ El,
                                                   const unsigned short* __restrict__ Ch,
                                                   const unsigned short* __restrict__ Cl,
                                                   const unsigned short* __restrict__ Hh,
                                                   const unsigned short* __restrict__ Hl,
                                                   const unsigned short* __restrict__ Wh,
                                                   const unsigned short* __restrict__ Wl,
                                                   const float* __restrict__ b_ih,
                                                   const float* __restrict__ b_hh,
                                                   float* __restrict__ cbuf,
                                                   unsigned short* __restrict__ Hoh,
                                                   unsigned short* __restrict__ Hol) {
    __shared__ short As[8 * 512];
    __shared__ short Bs[8 * 512];
    int t = threadIdx.x;
    int l = t & 63;
    int w = t >> 6;
    int wg = blockIdx.y * 32 + blockIdx.x;
    int xcd = wg & 7, lid = wg >> 3;
    int nb = xcd * 4 + (lid & 3);
    int mb = lid >> 2;
    int m0 = mb * 64;
    int n0 = nb * 64;
    int srow = l & 15;
    int koct = 8 * (l >> 4);
    int pl = w & 1;
    int mtA = w >> 1;
    int rowA = m0 + mtA * 16 + srow;
    int rowB = rowA + 32;
    int tokA = tok[rowA];
    int tokB = tok[rowB];
    const unsigned short* Ep = pl ? El : Eh;
    const unsigned short* Cp = pl ? Cl : Ch;
    const unsigned short* Hp = pl ? Hl : Hh;
    const unsigned short* Wp = pl ? Wl : Wh;
    const unsigned short* Wp0 = Wp + (size_t)(n0 + (w >> 1) * 16 + srow) * 1280 + koct;

    f32x4 z = {0.f, 0.f, 0.f, 0.f};
    f32x4 acc[2][2];
#pragma unroll
    for (int i = 0; i < 2; ++i)
#pragma unroll
        for (int j = 0; j < 2; ++j) acc[i][j] = z;

    int wm = w >> 1, wn = w & 1;
    short8 rA0, rA1, rB0, rB1;

#define GATES_LOADA(dst, row, tk, kk)                                          \
    {                                                                          \
        int kx = (kk);                                                         \
        if (kx < 256)      dst = *(const short8*)&Ep[(size_t)(tk)*256 + kx];   \
        else if (kx < 768) dst = *(const short8*)&Cp[(size_t)(row)*512 + (kx - 256)]; \
        else               dst = *(const short8*)&Hp[(size_t)(row)*512 + (kx - 768)]; \
    }

    GATES_LOADA(rA0, rowA, tokA, koct);
    GATES_LOADA(rA1, rowB, tokB, koct);
    rB0 = *(const short8*)(Wp0);
    rB1 = *(const short8*)(Wp0 + 32 * 1280);

    for (int kt = 0; kt < 1280; kt += 32) {
        __syncthreads();
        *(short8*)&As[(w)*512 + l * 8] = rA0;
        *(short8*)&As[(w + 4) * 512 + l * 8] = rA1;
        *(short8*)&Bs[(w)*512 + l * 8] = rB0;
        *(short8*)&Bs[(w + 4) * 512 + l * 8] = rB1;
        __syncthreads();
        if (kt + 32 < 1280) {
            GATES_LOADA(rA0, rowA, tokA, kt + 32 + koct);
            GATES_LOADA(rA1, rowB, tokB, kt + 32 + koct);
            rB0 = *(const short8*)(Wp0 + kt + 32);
            rB1 = *(const short8*)(Wp0 + 32 * 1280 + kt + 32);
        }
        short8 ah[2], al2[2], bh[2], bl2[2];
#pragma unroll
        for (int i = 0; i < 2; ++i) {
            ah[i] = *(short8*)&As[((wm * 2 + i) * 2 + 0) * 512 + l * 8];
            al2[i] = *(short8*)&As[((wm * 2 + i) * 2 + 1) * 512 + l * 8];
        }
#pragma unroll
        for (int j = 0; j < 2; ++j) {
            bh[j] = *(short8*)&Bs[((wn * 2 + j) * 2 + 0) * 512 + l * 8];
            bl2[j] = *(short8*)&Bs[((wn * 2 + j) * 2 + 1) * 512 + l * 8];
        }
#pragma unroll
        for (int i = 0; i < 2; ++i)
#pragma unroll
            for (int j = 0; j < 2; ++j) {
                acc[i][j] = __builtin_amdgcn_mfma_f32_16x16x32_bf16(ah[i], bh[j], acc[i][j], 0, 0, 0);
                acc[i][j] = __builtin_amdgcn_mfma_f32_16x16x32_bf16(ah[i], bl2[j], acc[i][j], 0, 0, 0);
                acc[i][j] = __builtin_amdgcn_mfma_f32_16x16x32_bf16(al2[i], bh[j], acc[i][j], 0, 0, 0);
            }
    }

    // LSTM epilogue: col gc -> gate gc&3 of d = gc>>2; lanes (cl&3)==0 own d.
    int r0 = (l >> 4) * 4;
    int cl = l & 15;
    bool act = (cl & 3) == 0;
#pragma unroll
    for (int j = 0; j < 2; ++j) {
        int gc = n0 + wn * 32 + j * 16 + cl;
        int d = gc >> 2;
        float bi_ = b_ih[d] + b_hh[d];
        float bf_ = b_ih[512 + d] + b_hh[512 + d];
        float bg_ = b_ih[1024 + d] + b_hh[1024 + d];
        float bo_ = b_ih[1536 + d] + b_hh[1536 + d];
#pragma unroll
        for (int i = 0; i < 2; ++i) {
#pragma unroll
            for (int r = 0; r < 4; ++r) {
                float x = acc[i][j][r];
                float x1 = __shfl_xor(x, 1);
                float x2 = __shfl_xor(x, 2);
                float x3 = __shfl_xor(x, 3);
                if (act) {
                    int row = m0 + wm * 32 + i * 16 + r0 + r;
                    float ig = sigm(x + bi_);
                    float fg = sigm(x1 + bf_);
                    float gg = tanhf(x2 + bg_);
                    float og = sigm(x3 + bo_);
                    float cn = fg * cbuf[(size_t)row * D_ + d] + ig * gg;
                    cbuf[(size_t)row * D_ + d] = cn;
                    float hv = og * tanhf(cn);
                    unsigned short hh = bf16_rn(hv);
                    Hoh[(size_t)row * D_ + d] = hh;
                    Hol[(size_t)row * D_ + d] = bf16_rn(hv - bf16f(hh));
                }
            }
        }
    }
}

// ---------------------------------------------------------------------------
extern "C" void kernel_launch(void* const* d_in, const int* in_sizes, int n_in,
                              void* d_out, int out_size, void* d_ws, size_t ws_size,
                              hipStream_t stream) {
    const float* ctx    = (const float*)d_in[0];
    const int*   counts = (const int*)d_in[1];
    const float* emb    = (const float*)d_in[3];
    const float* W_attn = (const float*)d_in[4];
    const float* W_ih   = (const float*)d_in[5];
    const float* b_ih   = (const float*)d_in[6];
    const float* W_hh   = (const float*)d_in[7];
    const float* b_hh   = (const float*)d_in[8];
    const float* W_proj = (const float*)d_in[9];
    const float* b_proj = (const float*)d_in[10];
    float* out = (float*)d_out;

    float* qbuf = (float*)d_ws;                 // [512][512]
    float* cbuf = qbuf + B_ * D_;               // [512][512]
    unsigned short* p = (unsigned short*)(cbuf + B_ * D_);
    unsigned short* Wa_hi = p; p += D_ * D_;
    unsigned short* Wa_lo = p; p += D_ * D_;
    unsigned short* Wp_hi = p; p += (size_t)V_ * D_;
    unsigned short* Wp_lo = p; p += (size_t)V_ * D_;
    unsigned short* Eb_hi = p; p += (size_t)V_ * E_;
    unsigned short* Eb_lo = p; p += (size_t)V_ * E_;
    unsigned short* Wg_hi = p; p += (size_t)G_ * 1280;
    unsigned short* Wg_lo = p; p += (size_t)G_ * 1280;
    unsigned short* hA_hi = p; p += B_ * D_;
    unsigned short* hA_lo = p; p += B_ * D_;
    unsigned short* hB_hi = p; p += B_ * D_;
    unsigned short* hB_lo = p; p += B_ * D_;
    unsigned short* cv_hi = p; p += B_ * D_;
    unsigned short* cv_lo = p; p += B_ * D_;
    int* tok = (int*)p;                         // [512]
    float* pvO = (float*)(tok + B_);            // [512][64]
    int* piO = (int*)(pvO + B_ * 64);           // [512][64]

    // one-time (per call) weight/emb conversions
    k_cvt<<<256, 256, 0, stream>>>(W_attn, Wa_hi, Wa_lo, D_ * D_ / 4);
    k_cvt<<<4096, 256, 0, stream>>>(W_proj, Wp_hi, Wp_lo, V_ * D_ / 4);
    k_cvt<<<2048, 256, 0, stream>>>(emb, Eb_hi, Eb_lo, V_ * E_ / 4);
    k_cvt_gates<<<2560, 256, 0, stream>>>(W_ih, W_hh, Wg_hi, Wg_lo);

    hipMemsetAsync(out, 0, (size_t)B_ * V_ * sizeof(float), stream);

    k_init<<<B_, 256, 0, stream>>>(ctx, counts, hA_hi, hA_lo, cbuf, tok);

    unsigned short *hin_hi = hA_hi, *hin_lo = hA_lo;
    unsigned short *hout_hi = hB_hi, *hout_lo = hB_lo;
    for (int t = 1; t < L_; ++t) {
        k_gemm<0><<<dim3(D_ / 128, B_ / 64), 256, 0, stream>>>(
            hin_hi, hin_lo, Wa_hi, Wa_lo, nullptr, qbuf, D_, nullptr, nullptr);
        k_attn<<<B_, 256, 0, stream>>>(ctx, counts, qbuf, cv_hi, cv_lo);
        k_gatesm<<<dim3(G_ / 64, B_ / 64), 256, 0, stream>>>(
            tok, Eb_hi, Eb_lo, cv_hi, cv_lo, hin_hi, hin_lo,
            Wg_hi, Wg_lo, b_ih, b_hh, cbuf, hout_hi, hout_lo);
        float* slab = out + (size_t)t * B_ * V_;
        k_gemm<1><<<dim3(V_ / 128, B_ / 64), 256, 0, stream>>>(
            hout_hi, hout_lo, Wp_hi, Wp_lo, b_proj, slab, V_, pvO, piO);
        if (t < L_ - 1) k_argmax_red<<<B_, 64, 0, stream>>>(pvO, piO, tok);
        unsigned short* tmp;
        tmp = hin_hi; hin_hi = hout_hi; hout_hi = tmp;
        tmp = hin_lo; hin_lo = hout_lo; hout_lo = tmp;
    }
}